// Round 1
// baseline (1015.356 us; speedup 1.0000x reference)
//
#include <hip/hip_runtime.h>

typedef _Float16 h2v __attribute__((ext_vector_type(2)));
typedef _Float16 h4v __attribute__((ext_vector_type(4)));
typedef _Float16 h8v __attribute__((ext_vector_type(8)));
typedef float    f4v __attribute__((ext_vector_type(4)));
typedef unsigned int u32;

#define RSTRIDE 272              // halves per padded row (256 + 16 pad) -> 544 B, 17*8192 B total
#define RBYTES  139264           // 256*272*2
#define P_OFF   139264
#define HS_OFF  141312
#define CS_OFF  141824
#define LDS_TOTAL 142336

__device__ inline f4v mfma16(h8v a, h8v b, f4v c) {
  return __builtin_amdgcn_mfma_f32_16x16x32_f16(a, b, c, 0, 0, 0);
}

__device__ inline float dot2f(u32 a, u32 b, float c) {
#if __has_builtin(__builtin_amdgcn_fdot2)
  return __builtin_amdgcn_fdot2(__builtin_bit_cast(h2v, a), __builtin_bit_cast(h2v, b), c, false);
#else
  h2v av = __builtin_bit_cast(h2v, a), bv = __builtin_bit_cast(h2v, b);
  return c + (float)av[0] * (float)bv[0] + (float)av[1] * (float)bv[1];
#endif
}

// Build padded/transposed fp16 copies of the shared matrices.
__global__ void prep_k(const float* __restrict__ Ww, const float* __restrict__ Wu,
                       const float* __restrict__ Wv, _Float16* __restrict__ wvt,
                       _Float16* __restrict__ wup, _Float16* __restrict__ wwh)
{
  int j = blockIdx.x, k = threadIdx.x;
  wvt[j * RSTRIDE + k] = (_Float16)Wv[k * 256 + j];   // WvT[j][k] = Wv[k][j]
  wup[j * RSTRIDE + k] = (_Float16)Wu[j * 256 + k];   // Wu padded row-major
  wwh[j * 256 + k]     = (_Float16)Ww[j * 256 + k];   // Ww plain row-major fp16
  if (k < 16) {
    wvt[j * RSTRIDE + 256 + k] = (_Float16)0.f;
    wup[j * RSTRIDE + 256 + k] = (_Float16)0.f;
  }
}

// out[b,i] = sum_j M[i,j] * V[b,j]   (used for beta = Ww@b and final x = Wv@c)
__global__ void matvec_k(const float* __restrict__ M, const float* __restrict__ V,
                         float* __restrict__ out)
{
  __shared__ float vb[256];
  int b = blockIdx.x, i = threadIdx.x;
  vb[i] = V[(size_t)b * 256 + i];
  __syncthreads();
  float a0 = 0.f;
#pragma unroll 8
  for (int j = 0; j < 256; j += 4) {
    f4v m = *(const f4v*)(M + (size_t)i * 256 + j);
    a0 += m[0] * vb[j] + m[1] * vb[j + 1] + m[2] * vb[j + 2] + m[3] * vb[j + 3];
  }
  out[(size_t)b * 256 + i] = a0;
}

// One workgroup per batch item:
//   GEMM1: T = w_b @ Wv      (A direct-global fp32->fp16, B = WvT in LDS) -> Tt in LDS
//   GEMM2: G^T = Tt @ Ww^T   (B direct-global fp16)                      -> G rows to regs
//   Recurrence: 20 x { h = relu(Wu h + beta - G c); c += h }            -> c to ws
#define LDA(base, kk, dst) { \
    f4v lo_ = *(const f4v*)((base) + (kk)*32 + 4*g); \
    f4v hi_ = *(const f4v*)((base) + (kk)*32 + 16 + 4*g); \
    dst[0]=(_Float16)lo_[0]; dst[1]=(_Float16)lo_[1]; dst[2]=(_Float16)lo_[2]; dst[3]=(_Float16)lo_[3]; \
    dst[4]=(_Float16)hi_[0]; dst[5]=(_Float16)hi_[1]; dst[6]=(_Float16)hi_[2]; dst[7]=(_Float16)hi_[3]; }

__global__ __launch_bounds__(512, 2) void rnn_mega(
    const float* __restrict__ w, const float* __restrict__ beta,
    const _Float16* __restrict__ wvt, const _Float16* __restrict__ wup,
    const _Float16* __restrict__ wwh, float* __restrict__ cout)
{
  extern __shared__ char smem[];
  _Float16* reg = (_Float16*)smem;                 // 139264 B region: WvT -> Tt -> G -> Wu
  float*    P   = (float*)(smem + P_OFF);          // 512 f32 partial sums
  _Float16* HS  = (_Float16*)(smem + HS_OFF);      // h scaled fp16 [256]
  _Float16* CS  = (_Float16*)(smem + CS_OFF);      // c scaled fp16 [256]

  const int tid  = threadIdx.x;
  const int wv   = tid >> 6;
  const int lane = tid & 63;
  const int g    = lane >> 4;
  const int l15  = lane & 15;
  const int B    = blockIdx.x;

  // ---- stage WvT into LDS ----
  {
    const uint4* src = (const uint4*)wvt;
    uint4* dst = (uint4*)smem;
#pragma unroll
    for (int r = 0; r < 17; ++r) dst[r * 512 + tid] = src[r * 512 + tid];
  }
  __syncthreads();

  f4v acc[2][16];
#pragma unroll
  for (int mt = 0; mt < 2; ++mt)
#pragma unroll
    for (int nt = 0; nt < 16; ++nt) acc[mt][nt] = f4v{0.f, 0.f, 0.f, 0.f};

  // ---- GEMM1: C[i,j] = sum_k w_b[i,k] * WvT[j,k] ----
  const float* gb0 = w + (size_t)B * 65536 + (size_t)(wv * 32 + l15) * 256;
  const float* gb1 = gb0 + 16 * 256;
  h8v a0c, a1c, a0n, a1n;
  LDA(gb0, 0, a0c); LDA(gb1, 0, a1c);
  for (int kk = 0; kk < 8; ++kk) {
    if (kk < 7) { LDA(gb0, kk + 1, a0n); LDA(gb1, kk + 1, a1n); }
#pragma unroll
    for (int nt = 0; nt < 16; ++nt) {
      const _Float16* bp = reg + (nt * 16 + l15) * RSTRIDE + kk * 32 + 4 * g;
      h4v blo = *(const h4v*)bp;
      h4v bhi = *(const h4v*)(bp + 16);
      h8v bf = __builtin_shufflevector(blo, bhi, 0, 1, 2, 3, 4, 5, 6, 7);
      acc[0][nt] = mfma16(a0c, bf, acc[0][nt]);
      acc[1][nt] = mfma16(a1c, bf, acc[1][nt]);
    }
    a0c = a0n; a1c = a1n;
  }
  __syncthreads();
  // store Tt[j=n][i=m] (transposed C write is the contiguous one), re-zero acc
#pragma unroll
  for (int mt = 0; mt < 2; ++mt)
#pragma unroll
    for (int nt = 0; nt < 16; ++nt) {
      int n = nt * 16 + l15;
      int m0 = wv * 32 + mt * 16 + g * 4;
      f4v a = acc[mt][nt];
      h4v t; t[0] = (_Float16)a[0]; t[1] = (_Float16)a[1]; t[2] = (_Float16)a[2]; t[3] = (_Float16)a[3];
      *(h4v*)(reg + n * RSTRIDE + m0) = t;
      acc[mt][nt] = f4v{0.f, 0.f, 0.f, 0.f};
    }
  __syncthreads();

  // ---- GEMM2: C[j,i] = sum_k Tt[j,k] * Ww[i,k]  ( = G[i,j] ) ----
  for (int kk = 0; kk < 8; ++kk) {
    const _Float16* ap0 = reg + (wv * 32 + l15) * RSTRIDE + kk * 32 + 4 * g;
    const _Float16* ap1 = ap0 + 16 * RSTRIDE;
    h4v a0lo = *(const h4v*)ap0, a0hi = *(const h4v*)(ap0 + 16);
    h4v a1lo = *(const h4v*)ap1, a1hi = *(const h4v*)(ap1 + 16);
    h8v a20 = __builtin_shufflevector(a0lo, a0hi, 0, 1, 2, 3, 4, 5, 6, 7);
    h8v a21 = __builtin_shufflevector(a1lo, a1hi, 0, 1, 2, 3, 4, 5, 6, 7);
#pragma unroll
    for (int nt = 0; nt < 16; ++nt) {
      const _Float16* b2p = wwh + (nt * 16 + l15) * 256 + kk * 32 + 4 * g;
      h4v blo = *(const h4v*)b2p;
      h4v bhi = *(const h4v*)(b2p + 16);
      h8v bf = __builtin_shufflevector(blo, bhi, 0, 1, 2, 3, 4, 5, 6, 7);
      acc[0][nt] = mfma16(a20, bf, acc[0][nt]);
      acc[1][nt] = mfma16(a21, bf, acc[1][nt]);
    }
  }
  __syncthreads();
  // store G[i=n][j=m] into region
#pragma unroll
  for (int mt = 0; mt < 2; ++mt)
#pragma unroll
    for (int nt = 0; nt < 16; ++nt) {
      int n = nt * 16 + l15;
      int m0 = wv * 32 + mt * 16 + g * 4;
      f4v a = acc[mt][nt];
      h4v t; t[0] = (_Float16)a[0]; t[1] = (_Float16)a[1]; t[2] = (_Float16)a[2]; t[3] = (_Float16)a[3];
      *(h4v*)(reg + n * RSTRIDE + m0) = t;
    }
  __syncthreads();

  // ---- pull my half-row of G into registers ----
  const int i  = tid & 255;
  const int h2 = tid >> 8;
  uint4 gq[16];
#pragma unroll
  for (int q = 0; q < 16; ++q)
    gq[q] = *(const uint4*)(smem + i * 544 + h2 * 256 + q * 16);
  float my_beta = beta[(size_t)B * 256 + i];
  __syncthreads();

  // ---- stage Wu into region (overwrites G copy; G now lives in regs) ----
  {
    const uint4* src = (const uint4*)wup;
    uint4* dst = (uint4*)smem;
#pragma unroll
    for (int r = 0; r < 17; ++r) dst[r * 512 + tid] = src[r * 512 + tid];
  }
  if (tid < 256) HS[tid] = (_Float16)0.f; else CS[tid - 256] = (_Float16)0.f;
  float cm = 0.f;
  __syncthreads();

  const uint4* wurow = (const uint4*)(smem + i * 544 + h2 * 256);
  const uint4* hrow  = (const uint4*)((const char*)HS + h2 * 256);
  const uint4* crow  = (const uint4*)((const char*)CS + h2 * 256);

  for (int t = 0; t < 20; ++t) {
    float au = 0.f, ag = 0.f;
#pragma unroll
    for (int q = 0; q < 16; ++q) {
      uint4 wu4 = wurow[q];
      uint4 hv  = hrow[q];
      au = dot2f(wu4.x, hv.x, au);
      au = dot2f(wu4.y, hv.y, au);
      au = dot2f(wu4.z, hv.z, au);
      au = dot2f(wu4.w, hv.w, au);
    }
#pragma unroll
    for (int q = 0; q < 16; ++q) {
      uint4 cv = crow[q];
      ag = dot2f(gq[q].x, cv.x, ag);
      ag = dot2f(gq[q].y, cv.y, ag);
      ag = dot2f(gq[q].z, cv.z, ag);
      ag = dot2f(gq[q].w, cv.w, ag);
    }
    P[tid] = (au - ag) * 128.f;   // descale 2^7
    __syncthreads();
    float y = my_beta + P[i] + P[i + 256];
    float hval = fmaxf(y, 0.f);
    if (h2 == 0) {
      cm += hval;
      HS[i] = (_Float16)(hval * 0.0078125f);  // * 2^-7
      CS[i] = (_Float16)(cm * 0.0078125f);
    }
    __syncthreads();
  }
  if (h2 == 0) cout[(size_t)B * 256 + i] = cm;
}

extern "C" void kernel_launch(void* const* d_in, const int* in_sizes, int n_in,
                              void* d_out, int out_size, void* d_ws, size_t ws_size,
                              hipStream_t stream)
{
  const float* w  = (const float*)d_in[0];
  const float* b  = (const float*)d_in[1];
  const float* Ww = (const float*)d_in[2];
  const float* Wu = (const float*)d_in[3];
  const float* Wv = (const float*)d_in[4];

  char* ws = (char*)d_ws;
  float*    beta = (float*)(ws);
  float*    cbuf = (float*)(ws + (size_t)2 * 1024 * 1024);
  _Float16* wvt  = (_Float16*)(ws + (size_t)4 * 1024 * 1024);
  _Float16* wup  = (_Float16*)(ws + (size_t)4 * 1024 * 1024 + RBYTES);
  _Float16* wwh  = (_Float16*)(ws + (size_t)4 * 1024 * 1024 + 2 * (size_t)RBYTES);

  (void)in_sizes; (void)n_in; (void)out_size; (void)ws_size;

  hipFuncSetAttribute((const void*)rnn_mega,
                      hipFuncAttributeMaxDynamicSharedMemorySize, LDS_TOTAL);

  prep_k<<<256, 256, 0, stream>>>(Ww, Wu, Wv, wvt, wup, wwh);
  matvec_k<<<2048, 256, 0, stream>>>(Ww, b, beta);                 // beta = Ww @ b
  rnn_mega<<<2048, 512, LDS_TOTAL, stream>>>(w, beta, wvt, wup, wwh, cbuf);
  matvec_k<<<2048, 256, 0, stream>>>(Wv, cbuf, (float*)d_out);     // x = Wv @ c
}

// Round 2
// 949.606 us; speedup vs baseline: 1.0692x; 1.0692x over previous
//
#include <hip/hip_runtime.h>

typedef _Float16 h2v __attribute__((ext_vector_type(2)));
typedef _Float16 h4v __attribute__((ext_vector_type(4)));
typedef _Float16 h8v __attribute__((ext_vector_type(8)));
typedef float    f4v __attribute__((ext_vector_type(4)));
typedef unsigned int u32;

#define RSTRIDE 272              // halves per padded row (256 + 16 pad) -> 544 B
#define RBYTES  139264           // 256*272*2
#define P_OFF   139264
#define HS_OFF  141312
#define CS_OFF  141824
#define LDS_TOTAL 142336

__device__ inline f4v mfma16(h8v a, h8v b, f4v c) {
  return __builtin_amdgcn_mfma_f32_16x16x32_f16(a, b, c, 0, 0, 0);
}

__device__ inline float dot2f(u32 a, u32 b, float c) {
#if __has_builtin(__builtin_amdgcn_fdot2)
  return __builtin_amdgcn_fdot2(__builtin_bit_cast(h2v, a), __builtin_bit_cast(h2v, b), c, false);
#else
  h2v av = __builtin_bit_cast(h2v, a), bv = __builtin_bit_cast(h2v, b);
  return c + (float)av[0] * (float)bv[0] + (float)av[1] * (float)bv[1];
#endif
}

// Build padded/transposed fp16 copies of the shared matrices.
__global__ void prep_k(const float* __restrict__ Ww, const float* __restrict__ Wu,
                       const float* __restrict__ Wv, _Float16* __restrict__ wvt,
                       _Float16* __restrict__ wup, _Float16* __restrict__ wwh)
{
  int j = blockIdx.x, k = threadIdx.x;
  wvt[j * RSTRIDE + k] = (_Float16)Wv[k * 256 + j];   // WvT[j][k] = Wv[k][j]
  wup[j * RSTRIDE + k] = (_Float16)Wu[j * 256 + k];   // Wu padded row-major
  wwh[j * 256 + k]     = (_Float16)Ww[j * 256 + k];   // Ww plain row-major fp16
  if (k < 16) {
    wvt[j * RSTRIDE + 256 + k] = (_Float16)0.f;
    wup[j * RSTRIDE + 256 + k] = (_Float16)0.f;
  }
}

// out[b,i] = sum_j M[i,j] * V[b,j]   (used for beta = Ww@b and final x = Wv@c)
__global__ void matvec_k(const float* __restrict__ M, const float* __restrict__ V,
                         float* __restrict__ out)
{
  __shared__ float vb[256];
  int b = blockIdx.x, i = threadIdx.x;
  vb[i] = V[(size_t)b * 256 + i];
  __syncthreads();
  float a0 = 0.f;
#pragma unroll 8
  for (int j = 0; j < 256; j += 4) {
    f4v m = *(const f4v*)(M + (size_t)i * 256 + j);
    a0 += m[0] * vb[j] + m[1] * vb[j + 1] + m[2] * vb[j + 2] + m[3] * vb[j + 3];
  }
  out[(size_t)b * 256 + i] = a0;
}

// One workgroup per batch item:
//   GEMM1: T = w_b @ Wv      (A direct-global fp32->fp16, B = WvT in LDS) -> Tt in LDS
//   GEMM2: G^T = Tt @ Ww^T   (B direct-global fp16)                      -> G rows to regs
//   Recurrence: 20 x { h = relu(Wu h + beta - G c); c += h }  with Wu AND G in registers
#define LDA(base, kk, dst) { \
    f4v lo_ = *(const f4v*)((base) + (kk)*32 + 4*g); \
    f4v hi_ = *(const f4v*)((base) + (kk)*32 + 16 + 4*g); \
    dst[0]=(_Float16)lo_[0]; dst[1]=(_Float16)lo_[1]; dst[2]=(_Float16)lo_[2]; dst[3]=(_Float16)lo_[3]; \
    dst[4]=(_Float16)hi_[0]; dst[5]=(_Float16)hi_[1]; dst[6]=(_Float16)hi_[2]; dst[7]=(_Float16)hi_[3]; }

__global__ __launch_bounds__(512, 2) void rnn_mega(
    const float* __restrict__ w, const float* __restrict__ beta,
    const _Float16* __restrict__ wvt, const _Float16* __restrict__ wup,
    const _Float16* __restrict__ wwh, float* __restrict__ cout)
{
  extern __shared__ char smem[];
  _Float16* reg = (_Float16*)smem;                 // 139264 B region: WvT -> Tt -> G
  float*    P   = (float*)(smem + P_OFF);          // 512 f32 partial sums
  _Float16* HS  = (_Float16*)(smem + HS_OFF);      // h scaled fp16 [256]
  _Float16* CS  = (_Float16*)(smem + CS_OFF);      // c scaled fp16 [256]

  const int tid  = threadIdx.x;
  const int wv   = tid >> 6;
  const int lane = tid & 63;
  const int g    = lane >> 4;
  const int l15  = lane & 15;
  const int B    = blockIdx.x;

  // ---- stage WvT into LDS ----
  {
    const uint4* src = (const uint4*)wvt;
    uint4* dst = (uint4*)smem;
#pragma unroll
    for (int r = 0; r < 17; ++r) dst[r * 512 + tid] = src[r * 512 + tid];
  }
  __syncthreads();

  f4v acc[2][16];
#pragma unroll
  for (int mt = 0; mt < 2; ++mt)
#pragma unroll
    for (int nt = 0; nt < 16; ++nt) acc[mt][nt] = f4v{0.f, 0.f, 0.f, 0.f};

  // ---- GEMM1: C[i,j] = sum_k w_b[i,k] * WvT[j,k] ----
  const float* gb0 = w + (size_t)B * 65536 + (size_t)(wv * 32 + l15) * 256;
  const float* gb1 = gb0 + 16 * 256;
  h8v a0c, a1c, a0n, a1n;
  LDA(gb0, 0, a0c); LDA(gb1, 0, a1c);
  for (int kk = 0; kk < 8; ++kk) {
    if (kk < 7) { LDA(gb0, kk + 1, a0n); LDA(gb1, kk + 1, a1n); }
#pragma unroll
    for (int nt = 0; nt < 16; ++nt) {
      const _Float16* bp = reg + (nt * 16 + l15) * RSTRIDE + kk * 32 + 4 * g;
      h4v blo = *(const h4v*)bp;
      h4v bhi = *(const h4v*)(bp + 16);
      h8v bf = __builtin_shufflevector(blo, bhi, 0, 1, 2, 3, 4, 5, 6, 7);
      acc[0][nt] = mfma16(a0c, bf, acc[0][nt]);
      acc[1][nt] = mfma16(a1c, bf, acc[1][nt]);
    }
    a0c = a0n; a1c = a1n;
  }
  __syncthreads();
  // store Tt[j=n][i=m] (transposed C write is the contiguous one), re-zero acc
#pragma unroll
  for (int mt = 0; mt < 2; ++mt)
#pragma unroll
    for (int nt = 0; nt < 16; ++nt) {
      int n = nt * 16 + l15;
      int m0 = wv * 32 + mt * 16 + g * 4;
      f4v a = acc[mt][nt];
      h4v t; t[0] = (_Float16)a[0]; t[1] = (_Float16)a[1]; t[2] = (_Float16)a[2]; t[3] = (_Float16)a[3];
      *(h4v*)(reg + n * RSTRIDE + m0) = t;
      acc[mt][nt] = f4v{0.f, 0.f, 0.f, 0.f};
    }
  __syncthreads();

  // ---- GEMM2: C[j,i] = sum_k Tt[j,k] * Ww[i,k]  ( = G[i,j] ) ----
  for (int kk = 0; kk < 8; ++kk) {
    const _Float16* ap0 = reg + (wv * 32 + l15) * RSTRIDE + kk * 32 + 4 * g;
    const _Float16* ap1 = ap0 + 16 * RSTRIDE;
    h4v a0lo = *(const h4v*)ap0, a0hi = *(const h4v*)(ap0 + 16);
    h4v a1lo = *(const h4v*)ap1, a1hi = *(const h4v*)(ap1 + 16);
    h8v a20 = __builtin_shufflevector(a0lo, a0hi, 0, 1, 2, 3, 4, 5, 6, 7);
    h8v a21 = __builtin_shufflevector(a1lo, a1hi, 0, 1, 2, 3, 4, 5, 6, 7);
#pragma unroll
    for (int nt = 0; nt < 16; ++nt) {
      const _Float16* b2p = wwh + (nt * 16 + l15) * 256 + kk * 32 + 4 * g;
      h4v blo = *(const h4v*)b2p;
      h4v bhi = *(const h4v*)(b2p + 16);
      h8v bf = __builtin_shufflevector(blo, bhi, 0, 1, 2, 3, 4, 5, 6, 7);
      acc[0][nt] = mfma16(a20, bf, acc[0][nt]);
      acc[1][nt] = mfma16(a21, bf, acc[1][nt]);
    }
  }
  __syncthreads();
  // store G[i=n][j=m] into region
#pragma unroll
  for (int mt = 0; mt < 2; ++mt)
#pragma unroll
    for (int nt = 0; nt < 16; ++nt) {
      int n = nt * 16 + l15;
      int m0 = wv * 32 + mt * 16 + g * 4;
      f4v a = acc[mt][nt];
      h4v t; t[0] = (_Float16)a[0]; t[1] = (_Float16)a[1]; t[2] = (_Float16)a[2]; t[3] = (_Float16)a[3];
      *(h4v*)(reg + n * RSTRIDE + m0) = t;
    }
  __syncthreads();

  // ---- pull my half-row of G into registers ----
  const int i  = tid & 255;
  const int h2 = tid >> 8;
  uint4 gq[16];
#pragma unroll
  for (int q = 0; q < 16; ++q)
    gq[q] = *(const uint4*)(smem + i * 544 + h2 * 256 + q * 16);
  float my_beta = beta[(size_t)B * 256 + i];

  // ---- pull my half-row of Wu into registers (from global fp16 copy, L2-hot) ----
  uint4 wq[16];
  {
    const uint4* wrow = (const uint4*)(wup + (size_t)i * RSTRIDE) + h2 * 16;
#pragma unroll
    for (int q = 0; q < 16; ++q) wq[q] = wrow[q];
  }

  if (tid < 256) HS[tid] = (_Float16)0.f; else CS[tid - 256] = (_Float16)0.f;
  float cm = 0.f;
  __syncthreads();

  const uint4* hrow = (const uint4*)((const char*)HS + h2 * 256);
  const uint4* crow = (const uint4*)((const char*)CS + h2 * 256);

  for (int t = 0; t < 20; ++t) {
    float au[4] = {0.f, 0.f, 0.f, 0.f};
    float ag[4] = {0.f, 0.f, 0.f, 0.f};
#pragma unroll
    for (int q = 0; q < 16; ++q) {
      uint4 wu4 = wq[q];
      uint4 gg  = gq[q];
      uint4 hv  = hrow[q];
      uint4 cv  = crow[q];
      float a = au[q & 3], e = ag[q & 3];
      a = dot2f(wu4.x, hv.x, a);
      a = dot2f(wu4.y, hv.y, a);
      a = dot2f(wu4.z, hv.z, a);
      a = dot2f(wu4.w, hv.w, a);
      e = dot2f(gg.x, cv.x, e);
      e = dot2f(gg.y, cv.y, e);
      e = dot2f(gg.z, cv.z, e);
      e = dot2f(gg.w, cv.w, e);
      au[q & 3] = a; ag[q & 3] = e;
    }
    float auf = (au[0] + au[1]) + (au[2] + au[3]);
    float agf = (ag[0] + ag[1]) + (ag[2] + ag[3]);
    P[tid] = (auf - agf) * 128.f;   // descale 2^7
    __syncthreads();
    float y = my_beta + P[i] + P[i + 256];
    float hval = fmaxf(y, 0.f);
    if (h2 == 0) {
      cm += hval;
      HS[i] = (_Float16)(hval * 0.0078125f);  // * 2^-7
      CS[i] = (_Float16)(cm * 0.0078125f);
    }
    __syncthreads();
  }
  if (h2 == 0) cout[(size_t)B * 256 + i] = cm;
}

extern "C" void kernel_launch(void* const* d_in, const int* in_sizes, int n_in,
                              void* d_out, int out_size, void* d_ws, size_t ws_size,
                              hipStream_t stream)
{
  const float* w  = (const float*)d_in[0];
  const float* b  = (const float*)d_in[1];
  const float* Ww = (const float*)d_in[2];
  const float* Wu = (const float*)d_in[3];
  const float* Wv = (const float*)d_in[4];

  char* ws = (char*)d_ws;
  float*    beta = (float*)(ws);
  float*    cbuf = (float*)(ws + (size_t)2 * 1024 * 1024);
  _Float16* wvt  = (_Float16*)(ws + (size_t)4 * 1024 * 1024);
  _Float16* wup  = (_Float16*)(ws + (size_t)4 * 1024 * 1024 + RBYTES);
  _Float16* wwh  = (_Float16*)(ws + (size_t)4 * 1024 * 1024 + 2 * (size_t)RBYTES);

  (void)in_sizes; (void)n_in; (void)out_size; (void)ws_size;

  hipFuncSetAttribute((const void*)rnn_mega,
                      hipFuncAttributeMaxDynamicSharedMemorySize, LDS_TOTAL);

  prep_k<<<256, 256, 0, stream>>>(Ww, Wu, Wv, wvt, wup, wwh);
  matvec_k<<<2048, 256, 0, stream>>>(Ww, b, beta);                 // beta = Ww @ b
  rnn_mega<<<2048, 512, LDS_TOTAL, stream>>>(w, beta, wvt, wup, wwh, cbuf);
  matvec_k<<<2048, 256, 0, stream>>>(Wv, cbuf, (float*)d_out);     // x = Wv @ c
}